// Round 1
// baseline (260.520 us; speedup 1.0000x reference)
//
#include <hip/hip_runtime.h>

typedef unsigned short u16;
typedef __attribute__((ext_vector_type(4))) unsigned int u32x4;
typedef __attribute__((ext_vector_type(4))) float f32x4;
typedef __attribute__((ext_vector_type(8))) __bf16 bf16x8;

// Problem constants (fixed by the reference).
constexpr int BATCH = 2;
constexpr int NV    = 20000;
constexpr int ND    = 8;
constexpr int CH    = 16;
constexpr int NF    = 16;
constexpr int NVD   = NV * ND;        // 160000 rows of y_flat per batch
constexpr int K0    = 1024;           // conv contraction (8 rings * 8 dirs * 16 ch)
constexpr int KE    = 1152;           // + center-kernel folded in (8 dirs * 16 ch)
constexpr int NCHUNK = KE / 32;       // 36 K-chunks of 32
constexpr int MTOT  = BATCH * NV;     // 40000 GEMM rows
constexpr int BSTR  = 40;             // padded B row stride in bf16 (32+8)

// ws layout (bytes):
//   [0, 10,240,000)              y16  : bf16 [B][NVD][CH]
//   [10,240,000, 10,534,912)     k2c  : bf16 [36][128][32]  (chunk-major weights)
//   [10,534,912, 102,694,912)    zc   : bf16 [36][40000][32] (chunk-major A matrix)
constexpr size_t Y16_OFF_B = 0;
constexpr size_t K2C_OFF_B = 10240000;
constexpr size_t ZC_OFF_B  = 10534912;   // total ws needed = 102,694,912 B

__device__ __forceinline__ u16 f2bf(float x) {
    unsigned int u = __float_as_uint(x);
    unsigned int r = (u + 0x7fffu + ((u >> 16) & 1u)) >> 16;   // RNE
    return (u16)r;
}
__device__ __forceinline__ unsigned int pack2bf(float a, float b) {
    return (unsigned int)f2bf(a) | ((unsigned int)f2bf(b) << 16);
}

// ---------------- P1: prep — y fp32 -> y16 table AND center chunks of zc ----------------
// one thread per (b,v,d): reads 16 floats, writes 32 B to y16 and 32 B to zc[32+(d>>1)].
__global__ __launch_bounds__(256) void prep(const float* __restrict__ y,
                                            u16* __restrict__ y16,
                                            u16* __restrict__ zc) {
    int tid = blockIdx.x * 256 + threadIdx.x;       // [0, 320000)
    const float4* src = (const float4*)(y + (size_t)tid * 16);
    float4 v0 = src[0], v1 = src[1], v2 = src[2], v3 = src[3];
    u32x4 lo = {pack2bf(v0.x, v0.y), pack2bf(v0.z, v0.w), pack2bf(v1.x, v1.y), pack2bf(v1.z, v1.w)};
    u32x4 hi = {pack2bf(v2.x, v2.y), pack2bf(v2.z, v2.w), pack2bf(v3.x, v3.y), pack2bf(v3.z, v3.w)};
    u16* yd = y16 + (size_t)tid * 16;
    *(u32x4*)(yd)     = lo;
    *(u32x4*)(yd + 8) = hi;
    int iv = tid >> 3, d = tid & 7;                 // iv = b*NV+v = GEMM row m
    u16* zd = zc + ((size_t)(32 + (d >> 1)) * MTOT + iv) * 32 + (d & 1) * 16;
    *(u32x4*)(zd)     = lo;
    *(u32x4*)(zd + 8) = hi;
}

// ---------------- P2: build rotated+extended weight matrix K2c ----------------
// K2c[kc][n][kk] = K2[k=kc*32+kk][n=w*16+f];  K2[(r,dd,c),(w,f)] = kernel[r,(dd-w)&7,c,f];
// ext rows (k>=1024, ke=d*16+c): (d==w) ? ck[c,f] : 0
__global__ __launch_bounds__(256) void k2_build(const float* __restrict__ kern,
                                                const float* __restrict__ ck,
                                                u16* __restrict__ k2c) {
    int e = blockIdx.x * 256 + threadIdx.x;   // [0, 36*4096)
    int i = e & 4095;
    int kc = e >> 12;
    int n = i >> 5, kk = i & 31;
    int k = kc * 32 + kk;
    int w = n >> 4, f = n & 15;
    float val;
    if (k < K0) {
        int r = k >> 7, dd = (k >> 4) & 7, c = k & 15;
        int d = (dd - w) & 7;
        val = kern[((r * 8 + d) * 16 + c) * 16 + f];
    } else {
        int ke = k - K0;
        int d = ke >> 4, c = ke & 15;
        val = (d == w) ? ck[c * 16 + f] : 0.f;
    }
    k2c[e] = f2bf(val);
}

// ---------------- G: gather + barycentric combine -> zc chunks 0..31 ----------------
// BATCH-MERGED: one thread per (v,rd) handles BOTH batches. Meta (contrib/wbary/angles)
// is batch-independent -> read once instead of twice (saves 46 MB of HBM fetch).
// Per thread: 9 coalesced meta loads + 12 independent 16 B gathered loads (deep MLP),
// writes 2x32 B; lane pairs still form full 64 B lines in zc at cols v and v+NV.
__global__ __launch_bounds__(256) void gather(const u16* __restrict__ y16,
                                              const int* __restrict__ contrib,
                                              const float* __restrict__ wbary,
                                              const int* __restrict__ angles,
                                              u16* __restrict__ zc) {
    int item = blockIdx.x * 256 + threadIdx.x;     // [0, 1,280,000)
    int v = item >> 6, rd = item & 63;             // wave = one vertex, 64 rd values
    size_t mb = ((size_t)v * 64 + rd) * 3;
    const u16* yb0 = y16;                          // batch 0 table
    const u16* yb1 = y16 + (size_t)NVD * CH;       // batch 1 table

    // meta: coalesced (wave reads 768 B contiguous per array)
    int   cn[3], an[3];
    float wj[3];
    #pragma unroll
    for (int j = 0; j < 3; ++j) {
        cn[j] = contrib[mb + j];
        an[j] = angles[mb + j];
        wj[j] = wbary[mb + j];
    }

    // issue all 12 gathered loads up front for memory-level parallelism
    u32x4 p0[3][2], p1[3][2];   // [j][half] for batch 0 / batch 1
    #pragma unroll
    for (int j = 0; j < 3; ++j) {
        size_t off = ((size_t)cn[j] * ND + an[j]) * CH;
        const u32x4* s0 = (const u32x4*)(yb0 + off);
        const u32x4* s1 = (const u32x4*)(yb1 + off);
        p0[j][0] = s0[0]; p0[j][1] = s0[1];
        p1[j][0] = s1[0]; p1[j][1] = s1[1];
    }

    float a0[CH], a1[CH];
    #pragma unroll
    for (int c = 0; c < CH; ++c) { a0[c] = 0.f; a1[c] = 0.f; }
    #pragma unroll
    for (int j = 0; j < 3; ++j) {
        float w = wj[j];
        #pragma unroll
        for (int h = 0; h < 2; ++h) {
            #pragma unroll
            for (int q = 0; q < 4; ++q) {
                unsigned int u0 = p0[j][h][q];
                unsigned int u1 = p1[j][h][q];
                a0[8 * h + 2 * q]     += w * __uint_as_float(u0 << 16);
                a0[8 * h + 2 * q + 1] += w * __uint_as_float(u0 & 0xffff0000u);
                a1[8 * h + 2 * q]     += w * __uint_as_float(u1 << 16);
                a1[8 * h + 2 * q + 1] += w * __uint_as_float(u1 & 0xffff0000u);
            }
        }
    }

    u32x4 o00, o01, o10, o11;
    #pragma unroll
    for (int q = 0; q < 4; ++q) {
        o00[q] = pack2bf(a0[2 * q],     a0[2 * q + 1]);
        o01[q] = pack2bf(a0[8 + 2 * q], a0[8 + 2 * q + 1]);
        o10[q] = pack2bf(a1[2 * q],     a1[2 * q + 1]);
        o11[q] = pack2bf(a1[8 + 2 * q], a1[8 + 2 * q + 1]);
    }
    size_t rowbase = (size_t)(rd >> 1) * MTOT;
    int half = (rd & 1) * 16;
    u16* d0 = zc + (rowbase + v) * 32 + half;          // batch 0: col v
    u16* d1 = zc + (rowbase + NV + v) * 32 + half;     // batch 1: col NV+v
    *(u32x4*)(d0)     = o00;
    *(u32x4*)(d0 + 8) = o01;
    *(u32x4*)(d1)     = o10;
    *(u32x4*)(d1 + 8) = o11;
}

// ---------------- M: GEMM (40000 x 1152 x 128) + bias + relu + max over w ----------------
// 625 blocks x 256 threads (4 waves). Wave w: rows m0+w*16..+15, all 128 cols.
// A: direct global->register (chunk-major zc => each wave's fragment load is a
// contiguous coalesced 1 KB). B: 288 KB L2-resident k2c, double-buffered in LDS,
// one barrier per chunk. Epilogue: lane's 8 nt accumulators are the 8 w-rotations
// of filter f=lane&15 -> in-register max, one exclusive store per (row,f).
__global__ __launch_bounds__(256) void gemm_max(const u16* __restrict__ zc,
                                                const u16* __restrict__ k2c,
                                                const float* __restrict__ bias,
                                                float* __restrict__ out) {
    __shared__ __align__(16) u16 Bb[2][128 * BSTR];   // 20,480 B
    const int t = threadIdx.x;
    const int w = t >> 6, lane = t & 63;
    const int lrow = lane & 15, lq = lane >> 4;
    const int m0 = blockIdx.x * 64;
    const int arow = m0 + w * 16 + lrow;

    // B staging helper: thread t stages n = t>>1, half = t&1 (32 B).
    const int sn = t >> 1, sh = (t & 1) * 16;

    // prologue: stage B[0], load A[0]
    {
        const u32x4* src = (const u32x4*)(k2c + (size_t)0 * 4096 + sn * 32 + sh);
        u32x4 b0 = src[0], b1 = src[1];
        u16* dst = &Bb[0][sn * BSTR + sh];
        *(u32x4*)(dst)     = b0;
        *(u32x4*)(dst + 8) = b1;
    }
    bf16x8 a_next = *(const bf16x8*)(zc + ((size_t)0 * MTOT + arow) * 32 + lq * 8);

    f32x4 acc[8];
    #pragma unroll
    for (int nt = 0; nt < 8; ++nt) acc[nt] = (f32x4){0.f, 0.f, 0.f, 0.f};

    for (int kc = 0; kc < NCHUNK; ++kc) {
        __syncthreads();                               // B[kc] visible; B[(kc+1)&1] free
        bf16x8 a = a_next;
        u32x4 bn0, bn1;
        if (kc < NCHUNK - 1) {
            a_next = *(const bf16x8*)(zc + ((size_t)(kc + 1) * MTOT + arow) * 32 + lq * 8);
            const u32x4* src = (const u32x4*)(k2c + (size_t)(kc + 1) * 4096 + sn * 32 + sh);
            bn0 = src[0]; bn1 = src[1];
        }
        bf16x8 bf[8];
        #pragma unroll
        for (int nt = 0; nt < 8; ++nt)
            bf[nt] = *(const bf16x8*)(&Bb[kc & 1][(nt * 16 + lrow) * BSTR + lq * 8]);
        #pragma unroll
        for (int nt = 0; nt < 8; ++nt)
            acc[nt] = __builtin_amdgcn_mfma_f32_16x16x32_bf16(a, bf[nt], acc[nt], 0, 0, 0);
        if (kc < NCHUNK - 1) {
            u16* dst = &Bb[(kc + 1) & 1][sn * BSTR + sh];
            *(u32x4*)(dst)     = bn0;
            *(u32x4*)(dst + 8) = bn1;
        }
    }

    // epilogue: +bias, relu, max over w (= max over nt), exclusive store
    const float bb = bias[lrow];
    #pragma unroll
    for (int reg = 0; reg < 4; ++reg) {
        float m = 0.f;   // relu floor
        #pragma unroll
        for (int nt = 0; nt < 8; ++nt) m = fmaxf(m, acc[nt][reg] + bb);
        out[((size_t)(m0 + w * 16 + lq * 4 + reg)) * NF + lrow] = m;
    }
}

extern "C" void kernel_launch(void* const* d_in, const int* in_sizes, int n_in,
                              void* d_out, int out_size, void* d_ws, size_t ws_size,
                              hipStream_t stream) {
    const float* y      = (const float*)d_in[0];
    const int*   contrib= (const int*)d_in[1];
    const float* wbary  = (const float*)d_in[2];
    const int*   angles = (const int*)d_in[3];
    const float* kern   = (const float*)d_in[4];
    const float* ck     = (const float*)d_in[5];
    const float* bias   = (const float*)d_in[6];
    float* out = (float*)d_out;

    u16* y16 = (u16*)((char*)d_ws + Y16_OFF_B);
    u16* k2c = (u16*)((char*)d_ws + K2C_OFF_B);
    u16* zc  = (u16*)((char*)d_ws + ZC_OFF_B);   // needs ws_size >= 102,694,912 B

    prep<<<1250, 256, 0, stream>>>(y, y16, zc);                                   // y16 + zc chunks 32..35
    k2_build<<<(NCHUNK * 4096) / 256, 256, 0, stream>>>(kern, ck, k2c);           // 576 blocks
    gather<<<5000, 256, 0, stream>>>(y16, contrib, wbary, angles, zc);            // zc chunks 0..31 (batch-merged)
    gemm_max<<<MTOT / 64, 256, 0, stream>>>(zc, k2c, bias, out);                  // 625 blocks
}

// Round 2
// 244.049 us; speedup vs baseline: 1.0675x; 1.0675x over previous
//
#include <hip/hip_runtime.h>

typedef unsigned short u16;
typedef __attribute__((ext_vector_type(4))) unsigned int u32x4;
typedef __attribute__((ext_vector_type(4))) float f32x4;
typedef __attribute__((ext_vector_type(8))) __bf16 bf16x8;

// Problem constants (fixed by the reference).
constexpr int BATCH = 2;
constexpr int NV    = 20000;
constexpr int ND    = 8;
constexpr int CH    = 16;
constexpr int NF    = 16;
constexpr int NVD   = NV * ND;        // 160000 rows of y_flat per batch
constexpr int K0    = 1024;           // conv contraction (8 rings * 8 dirs * 16 ch)
constexpr int KE    = 1152;           // + center-kernel folded in (8 dirs * 16 ch)
constexpr int NCHUNK = KE / 32;       // 36 K-chunks of 32
constexpr int MTOT  = BATCH * NV;     // 40000 GEMM rows
constexpr int BSTR  = 40;             // padded B row stride in bf16 (32+8)

// ws layout (bytes):
//   [0, 10,240,000)              y16  : bf16 [B][NVD][CH]
//   [10,240,000, 10,534,912)     k2c  : bf16 [36][128][32]  (chunk-major weights)
//   [10,534,912, 102,694,912)    zc   : bf16 [36][40000][32] (chunk-major A matrix)
constexpr size_t Y16_OFF_B = 0;
constexpr size_t K2C_OFF_B = 10240000;
constexpr size_t ZC_OFF_B  = 10534912;   // total ws needed = 102,694,912 B

__device__ __forceinline__ u16 f2bf(float x) {
    unsigned int u = __float_as_uint(x);
    unsigned int r = (u + 0x7fffu + ((u >> 16) & 1u)) >> 16;   // RNE
    return (u16)r;
}
__device__ __forceinline__ unsigned int pack2bf(float a, float b) {
    return (unsigned int)f2bf(a) | ((unsigned int)f2bf(b) << 16);
}

// ---------------- P1: prep — y fp32 -> y16 table AND center chunks of zc ----------------
// one thread per (b,v,d): reads 16 floats, writes 32 B to y16 and 32 B to zc[32+(d>>1)].
__global__ __launch_bounds__(256) void prep(const float* __restrict__ y,
                                            u16* __restrict__ y16,
                                            u16* __restrict__ zc) {
    int tid = blockIdx.x * 256 + threadIdx.x;       // [0, 320000)
    const float4* src = (const float4*)(y + (size_t)tid * 16);
    float4 v0 = src[0], v1 = src[1], v2 = src[2], v3 = src[3];
    u32x4 lo = {pack2bf(v0.x, v0.y), pack2bf(v0.z, v0.w), pack2bf(v1.x, v1.y), pack2bf(v1.z, v1.w)};
    u32x4 hi = {pack2bf(v2.x, v2.y), pack2bf(v2.z, v2.w), pack2bf(v3.x, v3.y), pack2bf(v3.z, v3.w)};
    u16* yd = y16 + (size_t)tid * 16;
    *(u32x4*)(yd)     = lo;
    *(u32x4*)(yd + 8) = hi;
    int iv = tid >> 3, d = tid & 7;                 // iv = b*NV+v = GEMM row m
    u16* zd = zc + ((size_t)(32 + (d >> 1)) * MTOT + iv) * 32 + (d & 1) * 16;
    *(u32x4*)(zd)     = lo;
    *(u32x4*)(zd + 8) = hi;
}

// ---------------- P2: build rotated+extended weight matrix K2c ----------------
// K2c[kc][n][kk] = K2[k=kc*32+kk][n=w*16+f];  K2[(r,dd,c),(w,f)] = kernel[r,(dd-w)&7,c,f];
// ext rows (k>=1024, ke=d*16+c): (d==w) ? ck[c,f] : 0
__global__ __launch_bounds__(256) void k2_build(const float* __restrict__ kern,
                                                const float* __restrict__ ck,
                                                u16* __restrict__ k2c) {
    int e = blockIdx.x * 256 + threadIdx.x;   // [0, 36*4096)
    int i = e & 4095;
    int kc = e >> 12;
    int n = i >> 5, kk = i & 31;
    int k = kc * 32 + kk;
    int w = n >> 4, f = n & 15;
    float val;
    if (k < K0) {
        int r = k >> 7, dd = (k >> 4) & 7, c = k & 15;
        int d = (dd - w) & 7;
        val = kern[((r * 8 + d) * 16 + c) * 16 + f];
    } else {
        int ke = k - K0;
        int d = ke >> 4, c = ke & 15;
        val = (d == w) ? ck[c * 16 + f] : 0.f;
    }
    k2c[e] = f2bf(val);
}

// ---------------- G: gather + barycentric combine -> zc chunks 0..31 ----------------
// rd-QUAD threads, single batch per thread (r1 lesson: keep per-thread gather working
// set inside ONE 5.12 MB y16 table; batch-major grid keeps the temporal window there too).
// One thread per (b, v, q) with q = rd/4. Meta for 4 rd-items = 48 B at a 48 B-aligned
// offset -> nine 16 B vector loads per FOUR items (2.25 meta-addrs/item vs 9 in r0).
// Stores are full 64 B zc lines (2 addrs/item). Gathers unchanged (6/item, irreducible).
// Lane-address count: 17 -> 10.25 per item; gather was address-issue-bound at r0.
__global__ __launch_bounds__(256) void gather(const u16* __restrict__ y16,
                                              const int* __restrict__ contrib,
                                              const float* __restrict__ wbary,
                                              const int* __restrict__ angles,
                                              u16* __restrict__ zc) {
    int tid = blockIdx.x * 256 + threadIdx.x;      // [0, 640,000)
    int iv = tid >> 4, q = tid & 15;               // iv = b*NV+v (batch-major), q = rd quad
    int b = iv >= NV;
    int v = iv - b * NV;
    size_t mb = ((size_t)v * 16 + q) * 12;         // element offset; byte = 48*(...) -> 16B aligned
    const u16* ybase = y16 + (size_t)b * NVD * CH;

    int4   c0 = *(const int4*)(contrib + mb);
    int4   c1 = *(const int4*)(contrib + mb + 4);
    int4   c2 = *(const int4*)(contrib + mb + 8);
    int4   A0 = *(const int4*)(angles + mb);
    int4   A1 = *(const int4*)(angles + mb + 4);
    int4   A2 = *(const int4*)(angles + mb + 8);
    float4 w0 = *(const float4*)(wbary + mb);
    float4 w1 = *(const float4*)(wbary + mb + 4);
    float4 w2 = *(const float4*)(wbary + mb + 8);

    int   cn[12] = {c0.x,c0.y,c0.z,c0.w, c1.x,c1.y,c1.z,c1.w, c2.x,c2.y,c2.z,c2.w};
    int   an[12] = {A0.x,A0.y,A0.z,A0.w, A1.x,A1.y,A1.z,A1.w, A2.x,A2.y,A2.z,A2.w};
    float wj[12] = {w0.x,w0.y,w0.z,w0.w, w1.x,w1.y,w1.z,w1.w, w2.x,w2.y,w2.z,w2.w};

    // two halves: half h covers rd = 4q+2h (s=0) and 4q+2h+1 (s=1); meta flat idx 6h+3s+j
    #pragma unroll
    for (int h = 0; h < 2; ++h) {
        // issue all 12 gathered 16 B loads up front (MLP)
        u32x4 p[6][2];
        #pragma unroll
        for (int e = 0; e < 6; ++e) {
            int fi = 6 * h + e;
            const u32x4* s = (const u32x4*)(ybase + ((size_t)cn[fi] * ND + an[fi]) * CH);
            p[e][0] = s[0];
            p[e][1] = s[1];
        }
        float acc[2][CH];
        #pragma unroll
        for (int s = 0; s < 2; ++s)
            #pragma unroll
            for (int c = 0; c < CH; ++c) acc[s][c] = 0.f;
        #pragma unroll
        for (int e = 0; e < 6; ++e) {
            int s = e / 3, j = e - 3 * s;
            float w = wj[6 * h + e];
            (void)j;
            #pragma unroll
            for (int g = 0; g < 2; ++g) {
                #pragma unroll
                for (int x = 0; x < 4; ++x) {
                    unsigned int u = p[e][g][x];
                    acc[s][8 * g + 2 * x]     += w * __uint_as_float(u << 16);
                    acc[s][8 * g + 2 * x + 1] += w * __uint_as_float(u & 0xffff0000u);
                }
            }
        }
        // pack 2 rd x 16 ch = one full 64 B zc line at (row 2q+h, col iv)
        u32x4 o[2][2];
        #pragma unroll
        for (int s = 0; s < 2; ++s)
            #pragma unroll
            for (int g = 0; g < 2; ++g)
                #pragma unroll
                for (int x = 0; x < 4; ++x)
                    o[s][g][x] = pack2bf(acc[s][8 * g + 2 * x], acc[s][8 * g + 2 * x + 1]);
        u16* dst = zc + ((size_t)(2 * q + h) * MTOT + iv) * 32;
        *(u32x4*)(dst)      = o[0][0];
        *(u32x4*)(dst + 8)  = o[0][1];
        *(u32x4*)(dst + 16) = o[1][0];
        *(u32x4*)(dst + 24) = o[1][1];
    }
}

// ---------------- M: GEMM (40000 x 1152 x 128) + bias + relu + max over w ----------------
// 625 blocks x 256 threads (4 waves). Wave w: rows m0+w*16..+15, all 128 cols.
// A: direct global->register (chunk-major zc => each wave's fragment load is a
// contiguous coalesced 1 KB). B: 288 KB L2-resident k2c, double-buffered in LDS,
// one barrier per chunk. Epilogue: lane's 8 nt accumulators are the 8 w-rotations
// of filter f=lane&15 -> in-register max, one exclusive store per (row,f).
__global__ __launch_bounds__(256) void gemm_max(const u16* __restrict__ zc,
                                                const u16* __restrict__ k2c,
                                                const float* __restrict__ bias,
                                                float* __restrict__ out) {
    __shared__ __align__(16) u16 Bb[2][128 * BSTR];   // 20,480 B
    const int t = threadIdx.x;
    const int w = t >> 6, lane = t & 63;
    const int lrow = lane & 15, lq = lane >> 4;
    const int m0 = blockIdx.x * 64;
    const int arow = m0 + w * 16 + lrow;

    // B staging helper: thread t stages n = t>>1, half = t&1 (32 B).
    const int sn = t >> 1, sh = (t & 1) * 16;

    // prologue: stage B[0], load A[0]
    {
        const u32x4* src = (const u32x4*)(k2c + (size_t)0 * 4096 + sn * 32 + sh);
        u32x4 b0 = src[0], b1 = src[1];
        u16* dst = &Bb[0][sn * BSTR + sh];
        *(u32x4*)(dst)     = b0;
        *(u32x4*)(dst + 8) = b1;
    }
    bf16x8 a_next = *(const bf16x8*)(zc + ((size_t)0 * MTOT + arow) * 32 + lq * 8);

    f32x4 acc[8];
    #pragma unroll
    for (int nt = 0; nt < 8; ++nt) acc[nt] = (f32x4){0.f, 0.f, 0.f, 0.f};

    for (int kc = 0; kc < NCHUNK; ++kc) {
        __syncthreads();                               // B[kc] visible; B[(kc+1)&1] free
        bf16x8 a = a_next;
        u32x4 bn0, bn1;
        if (kc < NCHUNK - 1) {
            a_next = *(const bf16x8*)(zc + ((size_t)(kc + 1) * MTOT + arow) * 32 + lq * 8);
            const u32x4* src = (const u32x4*)(k2c + (size_t)(kc + 1) * 4096 + sn * 32 + sh);
            bn0 = src[0]; bn1 = src[1];
        }
        bf16x8 bf[8];
        #pragma unroll
        for (int nt = 0; nt < 8; ++nt)
            bf[nt] = *(const bf16x8*)(&Bb[kc & 1][(nt * 16 + lrow) * BSTR + lq * 8]);
        #pragma unroll
        for (int nt = 0; nt < 8; ++nt)
            acc[nt] = __builtin_amdgcn_mfma_f32_16x16x32_bf16(a, bf[nt], acc[nt], 0, 0, 0);
        if (kc < NCHUNK - 1) {
            u16* dst = &Bb[(kc + 1) & 1][sn * BSTR + sh];
            *(u32x4*)(dst)     = bn0;
            *(u32x4*)(dst + 8) = bn1;
        }
    }

    // epilogue: +bias, relu, max over w (= max over nt), exclusive store
    const float bb = bias[lrow];
    #pragma unroll
    for (int reg = 0; reg < 4; ++reg) {
        float m = 0.f;   // relu floor
        #pragma unroll
        for (int nt = 0; nt < 8; ++nt) m = fmaxf(m, acc[nt][reg] + bb);
        out[((size_t)(m0 + w * 16 + lq * 4 + reg)) * NF + lrow] = m;
    }
}

extern "C" void kernel_launch(void* const* d_in, const int* in_sizes, int n_in,
                              void* d_out, int out_size, void* d_ws, size_t ws_size,
                              hipStream_t stream) {
    const float* y      = (const float*)d_in[0];
    const int*   contrib= (const int*)d_in[1];
    const float* wbary  = (const float*)d_in[2];
    const int*   angles = (const int*)d_in[3];
    const float* kern   = (const float*)d_in[4];
    const float* ck     = (const float*)d_in[5];
    const float* bias   = (const float*)d_in[6];
    float* out = (float*)d_out;

    u16* y16 = (u16*)((char*)d_ws + Y16_OFF_B);
    u16* k2c = (u16*)((char*)d_ws + K2C_OFF_B);
    u16* zc  = (u16*)((char*)d_ws + ZC_OFF_B);   // needs ws_size >= 102,694,912 B

    prep<<<1250, 256, 0, stream>>>(y, y16, zc);                                   // y16 + zc chunks 32..35
    k2_build<<<(NCHUNK * 4096) / 256, 256, 0, stream>>>(kern, ck, k2c);           // 576 blocks
    gather<<<2500, 256, 0, stream>>>(y16, contrib, wbary, angles, zc);            // zc chunks 0..31 (rd-quad)
    gemm_max<<<MTOT / 64, 256, 0, stream>>>(zc, k2c, bias, out);                  // 625 blocks
}